// Round 12
// baseline (113.527 us; speedup 1.0000x reference)
//
#include <hip/hip_runtime.h>
#include <hip/hip_bf16.h>

#define LOG2E 1.4426950408889634f
#define LN2   0.6931471805599453f
#define BIGP  (1.0e10f * LOG2E)   // BIG scaled into log2-domain

#define BATCH 32
#define SEQ   512
#define DIM   128
#define NMAT  128                   // 4 pairs * 32 batches

#define EXP2F(x) __builtin_amdgcn_exp2f(x)
#define LOG2F(x) __builtin_amdgcn_logf(x)

typedef short bf16x8 __attribute__((ext_vector_type(8)));
typedef float f32x4 __attribute__((ext_vector_type(4)));
typedef __attribute__((address_space(1))) const void gas_void;
typedef __attribute__((address_space(3))) void las_void;

// lane i <- lane i-1 (wave_shr:1). Boundary lanes overridden by caller.
__device__ __forceinline__ float dpp_shr1(float x) {
  return __int_as_float(__builtin_amdgcn_update_dpp(
      0, __float_as_int(x), 0x138, 0xF, 0xF, false));
}
// lane i <- lane i+1 (wave_shl:1). Boundary lanes overridden by caller.
__device__ __forceinline__ float dpp_shl1(float x) {
  return __int_as_float(__builtin_amdgcn_update_dpp(
      0, __float_as_int(x), 0x130, 0xF, 0xF, false));
}

// softmin' (log2 domain) via med3: mn - log2(1 + 2^(mn-md) + 2^(mn-mx))
__device__ __forceinline__ float softmin3(float a, float b, float c) {
  float mn = fminf(fminf(a, b), c);
  float md = __builtin_amdgcn_fmed3f(a, b, c);
  float mx = fmaxf(fmaxf(a, b), c);
  float sum = 1.0f + EXP2F(mn - md) + EXP2F(mn - mx);
  return mn - LOG2F(sum);
}

// ---------------------------------------------------------------------------
// Kernel 1 (prep): normalize rows, split to bf16 hi/lo, interleave.
// ---------------------------------------------------------------------------
__device__ __forceinline__ unsigned short f2bf_rn(float f) {
  unsigned u = __float_as_uint(f);
  u = (u + 0x7FFF + ((u >> 16) & 1)) >> 16;
  return (unsigned short)u;
}
__device__ __forceinline__ float bf2f(unsigned short h) {
  return __uint_as_float(((unsigned)h) << 16);
}

__global__ __launch_bounds__(256) void prep_kernel(
    const float* __restrict__ tgt, const float* __restrict__ oth,
    const float* __restrict__ x, unsigned short* __restrict__ Y) {
  int gid  = blockIdx.x * blockDim.x + threadIdx.x;
  int wave = gid >> 6;
  int lane = threadIdx.x & 63;
  int set = wave / (BATCH * SEQ);
  int row = wave % (BATCH * SEQ);
  const float* src = (set == 0) ? tgt : ((set == 1) ? oth : x);
  const float2* p = (const float2*)(src + (size_t)row * DIM);
  float2 v = p[lane];
  float s = v.x * v.x + v.y * v.y;
#pragma unroll
  for (int off = 32; off; off >>= 1) s += __shfl_xor(s, off);
  float inv = 1.0f / (sqrtf(s) + 1e-8f);
  float y0 = v.x * inv, y1 = v.y * inv;
  unsigned short h0 = f2bf_rn(y0);
  unsigned short l0 = f2bf_rn(y0 - bf2f(h0));
  unsigned short h1 = f2bf_rn(y1);
  unsigned short l1 = f2bf_rn(y1 - bf2f(h1));
  ushort4 st = {h0, l0, h1, l1};
  ((ushort4*)(Y + (size_t)wave * 256))[lane] = st;
}

// ---------------------------------------------------------------------------
// Kernel 2 (costmm): band-stripe bf16 MFMA GEMM -> Dband[i][d+32] (64 cols).
// Stripe s: A rows i in [64s,64s+64), B rows j in [64s-32,64s+96) (clamped).
// C = 64x128; band cells col=c-r in [0,64). Direct coalesced stores.
// Out-of-range j give garbage; dtw's L-span check masks them.
// ---------------------------------------------------------------------------
__global__ __launch_bounds__(256) void costmm_kernel(
    const unsigned short* __restrict__ Y, float* __restrict__ Dband) {
  __shared__ unsigned short As[64 * 64];       // 8 KB
  __shared__ unsigned short Bs[128 * 64];      // 16 KB

  const int s = blockIdx.x;                    // stripe 0..7
  const int m = blockIdx.y;
  const int p = m >> 5, b = m & 31;
  const int setA = (p == 1 || p == 3) ? 0 : 1;
  const int setB = (p <= 1) ? 2 : setA;
  const unsigned short* YA = Y + ((size_t)(setA * BATCH + b)) * SEQ * 256;
  const unsigned short* YB = Y + ((size_t)(setB * BATCH + b)) * SEQ * 256;
  const int i0 = s * 64;
  const int j0 = i0 - 32;

  const int t = threadIdx.x;
  const int w = t >> 6, l = t & 63;

  f32x4 acc[4][2];
#pragma unroll
  for (int a = 0; a < 4; ++a)
#pragma unroll
    for (int c = 0; c < 2; ++c) acc[a][c] = (f32x4){0.f, 0.f, 0.f, 0.f};

  const int srow_off = l >> 3;                                  // 0..7
  const int scb      = ((l & 7) * 16) ^ ((srow_off & 7) * 16);  // pre-swizzled col bytes

  for (int slab = 0; slab < 4; ++slab) {
    if (slab) __syncthreads();
#pragma unroll
    for (int q2 = 0; q2 < 2; ++q2) {           // A: 64 rows, 8 instrs
      int wi = w * 2 + q2;
      int r = wi * 8 + srow_off;
      const unsigned short* gA = YA + (size_t)(i0 + r) * 256 + slab * 64 + (scb >> 1);
      __builtin_amdgcn_global_load_lds((gas_void*)gA, (las_void*)(As + wi * 512), 16, 0, 0);
    }
#pragma unroll
    for (int q4 = 0; q4 < 4; ++q4) {           // B: 128 rows, 16 instrs
      int wi = w * 4 + q4;
      int r = wi * 8 + srow_off;               // 0..127
      int j = j0 + r; j = (j < 0) ? 0 : ((j > 511) ? 511 : j);
      const unsigned short* gB = YB + (size_t)j * 256 + slab * 64 + (scb >> 1);
      __builtin_amdgcn_global_load_lds((gas_void*)gB, (las_void*)(Bs + wi * 512), 16, 0, 0);
    }
    asm volatile("s_waitcnt vmcnt(0)" ::: "memory");
    __syncthreads();

#pragma unroll
    for (int ks = 0; ks < 2; ++ks) {
      bf16x8 af[4], bfr[2];
#pragma unroll
      for (int f = 0; f < 4; ++f) {
        int ra = f * 16 + (l & 15);
        int ca = (ks * 64 + (l >> 4) * 16) ^ ((ra & 7) << 4);
        af[f] = *(const bf16x8*)((const char*)As + ra * 128 + ca);
      }
#pragma unroll
      for (int f = 0; f < 2; ++f) {
        int rb = w * 32 + f * 16 + (l & 15);
        int cb = (ks * 64 + (l >> 4) * 16) ^ ((rb & 7) << 4);
        bfr[f] = *(const bf16x8*)((const char*)Bs + rb * 128 + cb);
      }
#pragma unroll
      for (int fm = 0; fm < 4; ++fm)
#pragma unroll
        for (int fn = 0; fn < 2; ++fn)
          acc[fm][fn] = __builtin_amdgcn_mfma_f32_16x16x32_bf16(
              af[fm], bfr[fn], acc[fm][fn], 0, 0, 0);
    }
  }

  // epilogue: direct predicated store; 16-lane contiguous runs per (fm,fn,q)
  float* Dbm = Dband + (size_t)m * (SEQ * 64);
#pragma unroll
  for (int fm = 0; fm < 4; ++fm)
#pragma unroll
    for (int fn = 0; fn < 2; ++fn)
#pragma unroll
      for (int q = 0; q < 4; ++q) {
        int r = fm * 16 + (l >> 4) * 4 + q;    // 0..63
        int c = w * 32 + fn * 16 + (l & 15);   // 0..127
        unsigned col = (unsigned)(c - r);      // d+32
        if (col < 64u)
          Dbm[((size_t)(i0 + r) << 6) + col] = (1.0f - acc[fm][fn][q]) * LOG2E;
      }
}

// ---------------------------------------------------------------------------
// Kernel 3 (dtw): banded (|d|<32) soft-DTW. ONE wave per block, 4 matrices:
// lanes 0-31 / 32-63 pack two matrices SIMD-wise (DPP boundary leakage lands
// exactly on the band-edge BIGP overrides); two chain-PAIRS (A,B) interleave
// in registers for ILP=2 latency hiding. Zero barriers.
// D read from Dband[i][d+32] via 4 per-matrix LDS rings [128][64];
// width-16 global_load_lds (4 rows/instr), counted vmcnt(16).
// ---------------------------------------------------------------------------
__global__ __launch_bounds__(64) void dtw_kernel(
    const float* __restrict__ Dband, float* __restrict__ raw) {
  __shared__ float stg[4][128][64];            // 128 KB
  const int t = threadIdx.x;
  const int half = t >> 5;                     // matrix within pair
  const int tp = t & 31;
  const int mb = blockIdx.x * 4;
  const float* Dm[4];
#pragma unroll
  for (int mi = 0; mi < 4; ++mi) Dm[mi] = Dband + (size_t)(mb + mi) * (SEQ * 64);

  const int d0 = 2 * tp - 32, d1 = d0 + 1;
  const int ad0 = (d0 < 0) ? -d0 : d0;
  const int ad1 = (d1 < 0) ? -d1 : d1;
  const int lo0 = 2 + ad0, span0 = 1022 - 2 * ad0;   // valid: lo<=L<=1024-|d|
  const int lo1 = 2 + ad1, span1 = 1022 - 2 * ad1;

  float v0A = (tp == 16) ? 0.0f : BIGP, v1A = BIGP;  // seed R[0][0]=0 (d=0)
  float v0B = (tp == 16) ? 0.0f : BIGP, v1B = BIGP;

  // stage 4 rows of matrix mi starting at row rb (multiple of 4)
#define STAGE4(MI_, RB_)                                                      \
  {                                                                           \
    int srow_ = (RB_) + (t >> 4); srow_ = (srow_ > 511) ? 511 : srow_;        \
    __builtin_amdgcn_global_load_lds(                                         \
        (gas_void*)(Dm[MI_] + ((size_t)srow_ << 6) + (t & 15) * 4),           \
        (las_void*)(&stg[MI_][(RB_) & 127][0]), 16, 0, 0);                    \
  }

  // prologue: rows 0..47 for all 4 matrices (48 instrs)
#pragma unroll
  for (int k = 0; k < 12; ++k) {
#pragma unroll
    for (int mi = 0; mi < 4; ++mi) STAGE4(mi, k * 4)
  }

  for (int c = 0; c < 32; ++c) {
    // issue rows [16c+48, 16c+64) for all 4 matrices (16 instrs)
    {
      int rbase = 16 * c + 48;
#pragma unroll
      for (int k = 0; k < 4; ++k) {
#pragma unroll
        for (int mi = 0; mi < 4; ++mi) STAGE4(mi, rbase + k * 4)
      }
    }
    // wait for everything except the 16 just issued -> prev chunk landed
    asm volatile("s_waitcnt vmcnt(16)" ::: "memory");

    // bulk rotate-read this chunk's D values (off the serial chain)
    float dvA[32], dvB[32];
    const int Lb = 32 * c + 1;                 // odd
#pragma unroll
    for (int q = 0; q < 32; ++q) {
      int L = Lb + q;
      int col = 2 * tp + (L & 1);              // d+32, 0..63
      int row = (L - col + 30) >> 1;           // data row i-1 (may be <0)
      dvA[q] = stg[half][row & 127][col];
      dvB[q] = stg[2 + half][row & 127][col];
    }

#pragma unroll
    for (int qq = 0; qq < 32; qq += 2) {
      const int Lo = Lb + qq;                  // odd step: update v1 (d1)
      const int Le = Lo + 1;                   // even step: update v0 (d0)
      {
        float dA = ((unsigned)(Lo - lo1) <= (unsigned)span1) ? dvA[qq] : BIGP;
        float dB = ((unsigned)(Lo - lo1) <= (unsigned)span1) ? dvB[qq] : BIGP;
        float aA = dpp_shl1(v0A); aA = (tp == 31) ? BIGP : aA;
        float aB = dpp_shl1(v0B); aB = (tp == 31) ? BIGP : aB;
        v1A = dA + softmin3(aA, v0A, v1A);
        v1B = dB + softmin3(aB, v0B, v1B);
      }
      {
        float dA = ((unsigned)(Le - lo0) <= (unsigned)span0) ? dvA[qq + 1] : BIGP;
        float dB = ((unsigned)(Le - lo0) <= (unsigned)span0) ? dvB[qq + 1] : BIGP;
        float bA = dpp_shr1(v1A); bA = (tp == 0) ? BIGP : bA;
        float bB = dpp_shr1(v1B); bB = (tp == 0) ? BIGP : bB;
        v0A = dA + softmin3(v1A, bA, v0A);
        v0B = dB + softmin3(v1B, bB, v0B);
      }
    }
  }
#undef STAGE4

  if (tp == 16) {
    raw[mb + half]     = v0A * LN2;            // R[512][512], d=0, L=1024
    raw[mb + 2 + half] = v0B * LN2;
  }
}

// ---------------------------------------------------------------------------
// Kernel 4: combine + MSE
// ---------------------------------------------------------------------------
__global__ __launch_bounds__(64) void combine_kernel(
    const float* __restrict__ raw, const float* __restrict__ labels,
    float* __restrict__ out) {
  int lane = threadIdx.x;
  float val = 0.0f;
  if (lane < BATCH) {
    float r0 = raw[0 * BATCH + lane];
    float r1 = raw[1 * BATCH + lane];
    float r2 = raw[2 * BATCH + lane];
    float r3 = raw[3 * BATCH + lane];
    float diff = r0 - r1 - 0.5f * r2 + 0.5f * r3;
    float e = diff - labels[lane];
    val = e * e;
  }
#pragma unroll
  for (int off = 32; off; off >>= 1) val += __shfl_xor(val, off);
  if (lane == 0) out[0] = val * (1.0f / BATCH);
}

// ---------------------------------------------------------------------------
extern "C" void kernel_launch(void* const* d_in, const int* in_sizes, int n_in,
                              void* d_out, int out_size, void* d_ws, size_t ws_size,
                              hipStream_t stream) {
  const float* TGT = (const float*)d_in[0];
  const float* OTH = (const float*)d_in[1];
  const float* X   = (const float*)d_in[2];
  const float* labels = (const float*)d_in[3];
  float* out = (float*)d_out;

  char* ws = (char*)d_ws;
  float* Dband = (float*)ws;                                   // 16.8 MB
  size_t dband_bytes = (size_t)NMAT * SEQ * 64 * 4;
  unsigned short* Y = (unsigned short*)(ws + dband_bytes);     // 24 MB
  float* raw = (float*)(ws + dband_bytes + (size_t)3 * BATCH * SEQ * 256 * 2);

  hipLaunchKernelGGL(prep_kernel, dim3((3 * BATCH * SEQ) / 4), dim3(256), 0, stream,
                     TGT, OTH, X, Y);
  hipLaunchKernelGGL(costmm_kernel, dim3(8, NMAT), dim3(256), 0, stream, Y, Dband);
  hipLaunchKernelGGL(dtw_kernel, dim3(NMAT / 4), dim3(64), 0, stream, Dband, raw);
  hipLaunchKernelGGL(combine_kernel, dim3(1), dim3(64), 0, stream, raw, labels, out);
}

// Round 13
// 69.402 us; speedup vs baseline: 1.6358x; 1.6358x over previous
//
#include <hip/hip_runtime.h>
#include <hip/hip_bf16.h>

#define LOG2E 1.4426950408889634f
#define LN2   0.6931471805599453f
#define BIGP  (1.0e10f * LOG2E)

#define BATCH 32
#define SEQ   512
#define DIM   128
#define NMAT  128                   // 4 pairs * 32 batches

#define EXP2F(x) __builtin_amdgcn_exp2f(x)
#define LOG2F(x) __builtin_amdgcn_logf(x)

typedef short bf16x8 __attribute__((ext_vector_type(8)));
typedef float f32x4 __attribute__((ext_vector_type(4)));
typedef __attribute__((address_space(1))) const void gas_void;
typedef __attribute__((address_space(3))) void las_void;

// lane i <- lane i-1 (wave_shr:1). Lane 0 receives old=0 (== +inf cost in W-domain).
__device__ __forceinline__ float dpp_shr1(float x) {
  return __int_as_float(__builtin_amdgcn_update_dpp(
      0, __float_as_int(x), 0x138, 0xF, 0xF, false));
}
// lane i <- lane i+1 (wave_shl:1). Lane 63 receives old=0.
__device__ __forceinline__ float dpp_shl1(float x) {
  return __int_as_float(__builtin_amdgcn_update_dpp(
      0, __float_as_int(x), 0x130, 0xF, 0xF, false));
}

// ---------------------------------------------------------------------------
// Kernel 1 (prep): normalize rows, split to bf16 hi/lo, interleave.
// ---------------------------------------------------------------------------
__device__ __forceinline__ unsigned short f2bf_rn(float f) {
  unsigned u = __float_as_uint(f);
  u = (u + 0x7FFF + ((u >> 16) & 1)) >> 16;
  return (unsigned short)u;
}
__device__ __forceinline__ float bf2f(unsigned short h) {
  return __uint_as_float(((unsigned)h) << 16);
}

__global__ __launch_bounds__(256) void prep_kernel(
    const float* __restrict__ tgt, const float* __restrict__ oth,
    const float* __restrict__ x, unsigned short* __restrict__ Y) {
  int gid  = blockIdx.x * blockDim.x + threadIdx.x;
  int wave = gid >> 6;
  int lane = threadIdx.x & 63;
  int set = wave / (BATCH * SEQ);
  int row = wave % (BATCH * SEQ);
  const float* src = (set == 0) ? tgt : ((set == 1) ? oth : x);
  const float2* p = (const float2*)(src + (size_t)row * DIM);
  float2 v = p[lane];
  float s = v.x * v.x + v.y * v.y;
#pragma unroll
  for (int off = 32; off; off >>= 1) s += __shfl_xor(s, off);
  float inv = 1.0f / (sqrtf(s) + 1e-8f);
  float y0 = v.x * inv, y1 = v.y * inv;
  unsigned short h0 = f2bf_rn(y0);
  unsigned short l0 = f2bf_rn(y0 - bf2f(h0));
  unsigned short h1 = f2bf_rn(y1);
  unsigned short l1 = f2bf_rn(y1 - bf2f(h1));
  ushort4 st = {h0, l0, h1, l1};
  ((ushort4*)(Y + (size_t)wave * 256))[lane] = st;
}

// ---------------------------------------------------------------------------
// Kernel 2 (costmm): round-11 version (verified, absmax 0.0156).
// Band-stripe bf16 MFMA GEMM -> Dband[i][d+64] (128 cols) direct store.
// Stripe s: A rows [64s,64s+64), B rows [64s-64,64s+128) clamped; C=64x192.
// ---------------------------------------------------------------------------
__global__ __launch_bounds__(256) void costmm_kernel(
    const unsigned short* __restrict__ Y, float* __restrict__ Dband) {
  __shared__ unsigned short As[64 * 64];       // 8 KB
  __shared__ unsigned short Bs[192 * 64];      // 24 KB

  const int s = blockIdx.x;                    // stripe 0..7
  const int m = blockIdx.y;
  const int p = m >> 5, b = m & 31;
  const int setA = (p == 1 || p == 3) ? 0 : 1;
  const int setB = (p <= 1) ? 2 : setA;
  const unsigned short* YA = Y + ((size_t)(setA * BATCH + b)) * SEQ * 256;
  const unsigned short* YB = Y + ((size_t)(setB * BATCH + b)) * SEQ * 256;
  const int i0 = s * 64;
  const int j0 = s * 64 - 64;

  const int t = threadIdx.x;
  const int w = t >> 6, l = t & 63;

  f32x4 acc[4][3];
#pragma unroll
  for (int a = 0; a < 4; ++a)
#pragma unroll
    for (int c = 0; c < 3; ++c) acc[a][c] = (f32x4){0.f, 0.f, 0.f, 0.f};

  const int srow_off = l >> 3;
  const int scb      = ((l & 7) * 16) ^ ((srow_off & 7) * 16);

  for (int slab = 0; slab < 4; ++slab) {
    if (slab) __syncthreads();
#pragma unroll
    for (int q2 = 0; q2 < 2; ++q2) {
      int wi = w * 2 + q2;
      int r = wi * 8 + srow_off;
      const unsigned short* gA = YA + (size_t)(i0 + r) * 256 + slab * 64 + (scb >> 1);
      __builtin_amdgcn_global_load_lds((gas_void*)gA, (las_void*)(As + wi * 512), 16, 0, 0);
    }
#pragma unroll
    for (int q6 = 0; q6 < 6; ++q6) {
      int wi = w * 6 + q6;
      int r = wi * 8 + srow_off;               // 0..191
      int j = j0 + r; j = (j < 0) ? 0 : ((j > 511) ? 511 : j);
      const unsigned short* gB = YB + (size_t)j * 256 + slab * 64 + (scb >> 1);
      __builtin_amdgcn_global_load_lds((gas_void*)gB, (las_void*)(Bs + wi * 512), 16, 0, 0);
    }
    asm volatile("s_waitcnt vmcnt(0)" ::: "memory");
    __syncthreads();

#pragma unroll
    for (int ks = 0; ks < 2; ++ks) {
      bf16x8 af[4], bfr[3];
#pragma unroll
      for (int f = 0; f < 4; ++f) {
        int ra = f * 16 + (l & 15);
        int ca = (ks * 64 + (l >> 4) * 16) ^ ((ra & 7) << 4);
        af[f] = *(const bf16x8*)((const char*)As + ra * 128 + ca);
      }
#pragma unroll
      for (int f = 0; f < 3; ++f) {
        int rb = w * 48 + f * 16 + (l & 15);
        int cb = (ks * 64 + (l >> 4) * 16) ^ ((rb & 7) << 4);
        bfr[f] = *(const bf16x8*)((const char*)Bs + rb * 128 + cb);
      }
#pragma unroll
      for (int fm = 0; fm < 4; ++fm)
#pragma unroll
        for (int fn = 0; fn < 3; ++fn)
          acc[fm][fn] = __builtin_amdgcn_mfma_f32_16x16x32_bf16(
              af[fm], bfr[fn], acc[fm][fn], 0, 0, 0);
    }
  }

  float* Dbm = Dband + (size_t)m * (SEQ * 128);
#pragma unroll
  for (int fm = 0; fm < 4; ++fm)
#pragma unroll
    for (int fn = 0; fn < 3; ++fn)
#pragma unroll
      for (int q = 0; q < 4; ++q) {
        int r = fm * 16 + (l >> 4) * 4 + q;    // 0..63
        int c = w * 48 + fn * 16 + (l & 15);   // 0..191
        unsigned crm = (unsigned)(c - r);      // d+64
        if (crm < 128u)
          Dbm[((size_t)(i0 + r) << 7) + crm] = (1.0f - acc[fm][fn][q]) * LOG2E;
      }
}

// ---------------------------------------------------------------------------
// Kernel 3 (dtw): banded soft-DTW in LINEAR domain. One wave/matrix, no
// barriers. W = 2^(-R + o): per half-step  W_new = s * (Wa + Wb + Wc),
// s = 2^(-D') precomputed OFF-chain (validity folded in as s=0; DPP old=0
// supplies band-edge zeros). Per-chunk exponent renormalization.
// Staging/gather identical to round 11 (verified).
// ---------------------------------------------------------------------------
__global__ __launch_bounds__(64) void dtw_kernel(
    const float* __restrict__ Dband, float* __restrict__ raw) {
  __shared__ float stg[128][128];              // 64 KB ring (row = i & 127)
  const int t = threadIdx.x;
  const int m = blockIdx.x;
  const float* Db = Dband + (size_t)m * (SEQ * 128);

  const int d0 = 2 * t - 64, d1 = d0 + 1;
  const int ad0 = (d0 < 0) ? -d0 : d0;
  const int ad1 = (d1 < 0) ? -d1 : d1;
  const int lo0 = 2 + ad0, span0 = 1022 - 2 * ad0;   // valid: lo<=L<=1024-|d|
  const int lo1 = 2 + ad1, span1 = 1022 - 2 * ad1;

  float v0 = (t == 32) ? 1.0f : 0.0f;          // W[0][0] = 2^0 (R=0) at d=0
  float v1 = 0.0f;
  int otally = 0;

  // prologue: stage rows 0..63 (32 instrs, 2 rows/instr)
#pragma unroll
  for (int q = 0; q < 32; ++q) {
    int row = q * 2;
    __builtin_amdgcn_global_load_lds(
        (gas_void*)(Db + (size_t)row * 128 + t * 4),
        (las_void*)(&stg[row][0]), 16, 0, 0);
  }

  for (int c = 0; c < 32; ++c) {
    // issue next 16 rows [16c+64, 16c+80) (8 instrs; source rows clamped)
    {
      int rbase = 16 * c + 64;
#pragma unroll
      for (int q = 0; q < 8; ++q) {
        int row = rbase + q * 2;
        int srow = row + (t >> 5);
        srow = (srow > 511) ? 511 : srow;
        __builtin_amdgcn_global_load_lds(
            (gas_void*)(Db + (size_t)srow * 128 + (t & 31) * 4),
            (las_void*)(&stg[row & 127][0]), 16, 0, 0);
      }
    }
    asm volatile("s_waitcnt vmcnt(8)" ::: "memory");

    // bulk: gather D', convert to s = valid ? 2^(-D') : 0   (all off-chain)
    float sv[32];
    const int Lb = 32 * c + 1;                 // odd
#pragma unroll
    for (int q = 0; q < 32; ++q) {
      int L = Lb + q;
      int col = 2 * t + (L & 1);               // d+64
      int row = (L - col + 62) >> 1;
      float d = stg[row & 127][col];
      float e2 = EXP2F(-d);
      unsigned rel = (unsigned)(L - ((q & 1) ? lo0 : lo1));
      unsigned spn = (unsigned)((q & 1) ? span0 : span1);
      sv[q] = (rel <= spn) ? e2 : 0.0f;
    }

    // serial chain: 16 cyc/half-step (dpp + add + add + mul)
#pragma unroll
    for (int qq = 0; qq < 32; qq += 2) {
      {  // odd L: v1 = s*(shl(v0) + v0 + v1)
        float a = dpp_shl1(v0);                // lane 63 -> 0
        v1 = sv[qq] * (a + v0 + v1);
      }
      {  // even L: v0 = s*(v1 + shr(v1) + v0)
        float bb = dpp_shr1(v1);               // lane 0 -> 0
        v0 = sv[qq + 1] * (v1 + bb + v0);
      }
    }

    // chunk-boundary renormalize: scale so wave-max W ~ 1
    float mx = fmaxf(v0, v1);
#pragma unroll
    for (int off = 32; off; off >>= 1) mx = fmaxf(mx, __shfl_xor(mx, off));
    int e = (int)((__float_as_uint(mx) >> 23) & 255u) - 127;
    float scale = __uint_as_float((unsigned)(127 - e) << 23);
    v0 *= scale; v1 *= scale;
    otally += e;
  }

  // R'[512][512] = -(log2(W) + sum(e)); raw = R' * ln2
  if (t == 32) raw[m] = -(LOG2F(v0) + (float)otally) * LN2;
}

// ---------------------------------------------------------------------------
// Kernel 4: combine + MSE
// ---------------------------------------------------------------------------
__global__ __launch_bounds__(64) void combine_kernel(
    const float* __restrict__ raw, const float* __restrict__ labels,
    float* __restrict__ out) {
  int lane = threadIdx.x;
  float val = 0.0f;
  if (lane < BATCH) {
    float r0 = raw[0 * BATCH + lane];
    float r1 = raw[1 * BATCH + lane];
    float r2 = raw[2 * BATCH + lane];
    float r3 = raw[3 * BATCH + lane];
    float diff = r0 - r1 - 0.5f * r2 + 0.5f * r3;
    float e = diff - labels[lane];
    val = e * e;
  }
#pragma unroll
  for (int off = 32; off; off >>= 1) val += __shfl_xor(val, off);
  if (lane == 0) out[0] = val * (1.0f / BATCH);
}

// ---------------------------------------------------------------------------
extern "C" void kernel_launch(void* const* d_in, const int* in_sizes, int n_in,
                              void* d_out, int out_size, void* d_ws, size_t ws_size,
                              hipStream_t stream) {
  const float* TGT = (const float*)d_in[0];
  const float* OTH = (const float*)d_in[1];
  const float* X   = (const float*)d_in[2];
  const float* labels = (const float*)d_in[3];
  float* out = (float*)d_out;

  char* ws = (char*)d_ws;
  float* Dband = (float*)ws;                                   // 32 MB
  size_t dband_bytes = (size_t)NMAT * SEQ * 128 * 4;
  unsigned short* Y = (unsigned short*)(ws + dband_bytes);     // 24 MB
  float* raw = (float*)(ws + dband_bytes + (size_t)3 * BATCH * SEQ * 256 * 2);

  hipLaunchKernelGGL(prep_kernel, dim3((3 * BATCH * SEQ) / 4), dim3(256), 0, stream,
                     TGT, OTH, X, Y);
  hipLaunchKernelGGL(costmm_kernel, dim3(8, NMAT), dim3(256), 0, stream, Y, Dband);
  hipLaunchKernelGGL(dtw_kernel, dim3(NMAT), dim3(64), 0, stream, Dband, raw);
  hipLaunchKernelGGL(combine_kernel, dim3(1), dim3(64), 0, stream, raw, labels, out);
}

// Round 15
// 69.065 us; speedup vs baseline: 1.6438x; 1.0049x over previous
//
#include <hip/hip_runtime.h>
#include <hip/hip_bf16.h>

#define LOG2E 1.4426950408889634f
#define LN2   0.6931471805599453f
#define BIGP  (1.0e10f * LOG2E)

#define BATCH 32
#define SEQ   512
#define DIM   128
#define NMAT  128                   // 4 pairs * 32 batches

#define EXP2F(x) __builtin_amdgcn_exp2f(x)
#define LOG2F(x) __builtin_amdgcn_logf(x)

typedef short bf16x8 __attribute__((ext_vector_type(8)));
typedef float f32x4 __attribute__((ext_vector_type(4)));
typedef __attribute__((address_space(1))) const void gas_void;
typedef __attribute__((address_space(3))) void las_void;

// lane i <- lane i-1 (wave_shr:1), bound_ctrl: lane 0 receives 0 (== W for +inf cost)
__device__ __forceinline__ float dpp_shr1(float x) {
  return __int_as_float(__builtin_amdgcn_update_dpp(
      0, __float_as_int(x), 0x138, 0xF, 0xF, false));
}
// lane i <- lane i+1 (wave_shl:1), lane 63 receives 0
__device__ __forceinline__ float dpp_shl1(float x) {
  return __int_as_float(__builtin_amdgcn_update_dpp(
      0, __float_as_int(x), 0x130, 0xF, 0xF, false));
}
// x = max(x, dpp<CTRL>(x)); lanes w/o source keep x (old = x)
template <int CTRL>
__device__ __forceinline__ float dpp_max(float x) {
  int y = __builtin_amdgcn_update_dpp(
      __float_as_int(x), __float_as_int(x), CTRL, 0xF, 0xF, false);
  return fmaxf(x, __int_as_float(y));
}

// ---------------------------------------------------------------------------
// Kernel 1 (prep): normalize rows, split to bf16 hi/lo, interleave.
// ---------------------------------------------------------------------------
__device__ __forceinline__ unsigned short f2bf_rn(float f) {
  unsigned u = __float_as_uint(f);
  u = (u + 0x7FFF + ((u >> 16) & 1)) >> 16;
  return (unsigned short)u;
}
__device__ __forceinline__ float bf2f(unsigned short h) {
  return __uint_as_float(((unsigned)h) << 16);
}

__global__ __launch_bounds__(256) void prep_kernel(
    const float* __restrict__ tgt, const float* __restrict__ oth,
    const float* __restrict__ x, unsigned short* __restrict__ Y) {
  int gid  = blockIdx.x * blockDim.x + threadIdx.x;
  int wave = gid >> 6;
  int lane = threadIdx.x & 63;
  int set = wave / (BATCH * SEQ);
  int row = wave % (BATCH * SEQ);
  const float* src = (set == 0) ? tgt : ((set == 1) ? oth : x);
  const float2* p = (const float2*)(src + (size_t)row * DIM);
  float2 v = p[lane];
  float s = v.x * v.x + v.y * v.y;
#pragma unroll
  for (int off = 32; off; off >>= 1) s += __shfl_xor(s, off);
  float inv = 1.0f / (sqrtf(s) + 1e-8f);
  float y0 = v.x * inv, y1 = v.y * inv;
  unsigned short h0 = f2bf_rn(y0);
  unsigned short l0 = f2bf_rn(y0 - bf2f(h0));
  unsigned short h1 = f2bf_rn(y1);
  unsigned short l1 = f2bf_rn(y1 - bf2f(h1));
  ushort4 st = {h0, l0, h1, l1};
  ((ushort4*)(Y + (size_t)wave * 256))[lane] = st;
}

// ---------------------------------------------------------------------------
// Kernel 2 (costmm): band-stripe bf16 MFMA GEMM.
// Stores s = 2^(-D') in Sband[i][d+64] (linear-domain weight), with
// j-validity folded in: out-of-range j -> 0 (== +inf cost).
// Stripe s: A rows [64s,64s+64), B rows [64s-64,64s+128) clamped; C=64x192.
// ---------------------------------------------------------------------------
__global__ __launch_bounds__(256) void costmm_kernel(
    const unsigned short* __restrict__ Y, float* __restrict__ Sband) {
  __shared__ unsigned short As[64 * 64];       // 8 KB
  __shared__ unsigned short Bs[192 * 64];      // 24 KB

  const int s = blockIdx.x;                    // stripe 0..7
  const int m = blockIdx.y;
  const int p = m >> 5, b = m & 31;
  const int setA = (p == 1 || p == 3) ? 0 : 1;
  const int setB = (p <= 1) ? 2 : setA;
  const unsigned short* YA = Y + ((size_t)(setA * BATCH + b)) * SEQ * 256;
  const unsigned short* YB = Y + ((size_t)(setB * BATCH + b)) * SEQ * 256;
  const int i0 = s * 64;
  const int j0 = s * 64 - 64;

  const int t = threadIdx.x;
  const int w = t >> 6, l = t & 63;

  f32x4 acc[4][3];
#pragma unroll
  for (int a = 0; a < 4; ++a)
#pragma unroll
    for (int c = 0; c < 3; ++c) acc[a][c] = (f32x4){0.f, 0.f, 0.f, 0.f};

  const int srow_off = l >> 3;
  const int scb      = ((l & 7) * 16) ^ ((srow_off & 7) * 16);

  for (int slab = 0; slab < 4; ++slab) {
    if (slab) __syncthreads();
#pragma unroll
    for (int q2 = 0; q2 < 2; ++q2) {
      int wi = w * 2 + q2;
      int r = wi * 8 + srow_off;
      const unsigned short* gA = YA + (size_t)(i0 + r) * 256 + slab * 64 + (scb >> 1);
      __builtin_amdgcn_global_load_lds((gas_void*)gA, (las_void*)(As + wi * 512), 16, 0, 0);
    }
#pragma unroll
    for (int q6 = 0; q6 < 6; ++q6) {
      int wi = w * 6 + q6;
      int r = wi * 8 + srow_off;               // 0..191
      int j = j0 + r; j = (j < 0) ? 0 : ((j > 511) ? 511 : j);
      const unsigned short* gB = YB + (size_t)j * 256 + slab * 64 + (scb >> 1);
      __builtin_amdgcn_global_load_lds((gas_void*)gB, (las_void*)(Bs + wi * 512), 16, 0, 0);
    }
    asm volatile("s_waitcnt vmcnt(0)" ::: "memory");
    __syncthreads();

#pragma unroll
    for (int ks = 0; ks < 2; ++ks) {
      bf16x8 af[4], bfr[3];
#pragma unroll
      for (int f = 0; f < 4; ++f) {
        int ra = f * 16 + (l & 15);
        int ca = (ks * 64 + (l >> 4) * 16) ^ ((ra & 7) << 4);
        af[f] = *(const bf16x8*)((const char*)As + ra * 128 + ca);
      }
#pragma unroll
      for (int f = 0; f < 3; ++f) {
        int rb = w * 48 + f * 16 + (l & 15);
        int cb = (ks * 64 + (l >> 4) * 16) ^ ((rb & 7) << 4);
        bfr[f] = *(const bf16x8*)((const char*)Bs + rb * 128 + cb);
      }
#pragma unroll
      for (int fm = 0; fm < 4; ++fm)
#pragma unroll
        for (int fn = 0; fn < 3; ++fn)
          acc[fm][fn] = __builtin_amdgcn_mfma_f32_16x16x32_bf16(
              af[fm], bfr[fn], acc[fm][fn], 0, 0, 0);
    }
  }

  float* Sbm = Sband + (size_t)m * (SEQ * 128);
#pragma unroll
  for (int fm = 0; fm < 4; ++fm)
#pragma unroll
    for (int fn = 0; fn < 3; ++fn)
#pragma unroll
      for (int q = 0; q < 4; ++q) {
        int r = fm * 16 + (l >> 4) * 4 + q;    // 0..63  (i = i0+r)
        int c = w * 48 + fn * 16 + (l & 15);   // 0..191 (j = j0+c)
        unsigned crm = (unsigned)(c - r);      // d+64
        if (crm < 128u) {
          int jreal = j0 + c;
          float dp = (1.0f - acc[fm][fn][q]) * LOG2E;
          float sval = ((unsigned)jreal < 512u) ? EXP2F(-dp) : 0.0f;
          Sbm[((size_t)(i0 + r) << 7) + crm] = sval;
        }
      }
}

// ---------------------------------------------------------------------------
// Kernel 3 (dtw): banded soft-DTW, linear domain, one wave/matrix, no
// barriers. W half-steps: W_new = s*(Wa+Wb+Wc); s read PRE-EXPONENTIATED
// from Sband (j-invalid already 0); i-validity = (unsigned)row<512 reusing
// the gather row index. Paired ds_read_b64 gather. DPP wave-max rescale.
// ---------------------------------------------------------------------------
__global__ __launch_bounds__(64) void dtw_kernel(
    const float* __restrict__ Sband, float* __restrict__ raw) {
  __shared__ float stg[128][128];              // 64 KB ring (row = i-1 & 127)
  const int t = threadIdx.x;
  const int m = blockIdx.x;
  const float* Db = Sband + (size_t)m * (SEQ * 128);

  float v0 = (t == 32) ? 1.0f : 0.0f;          // W[0][0] = 2^0 at d=0
  float v1 = 0.0f;
  int otally = 0;

  // prologue: stage rows 0..63 (32 instrs, 2 rows/instr)
#pragma unroll
  for (int q = 0; q < 32; ++q) {
    int row = q * 2;
    __builtin_amdgcn_global_load_lds(
        (gas_void*)(Db + (size_t)row * 128 + t * 4),
        (las_void*)(&stg[row][0]), 16, 0, 0);
  }

  for (int c = 0; c < 32; ++c) {
    // issue next 16 rows [16c+64, 16c+80) (8 instrs; source rows clamped)
    {
      int rbase = 16 * c + 64;
#pragma unroll
      for (int q = 0; q < 8; ++q) {
        int row = rbase + q * 2;
        int srow = row + (t >> 5);
        srow = (srow > 511) ? 511 : srow;
        __builtin_amdgcn_global_load_lds(
            (gas_void*)(Db + (size_t)srow * 128 + (t & 31) * 4),
            (las_void*)(&stg[row & 127][0]), 16, 0, 0);
      }
    }
    asm volatile("s_waitcnt vmcnt(8)" ::: "memory");

    // gather s-values: steps pair up on ring rows -> b64 reads
    float sv[32];
    const int Lb = 32 * c + 1;                 // odd
    const int ra = ((Lb + 61) >> 1) - t;       // row of q=0 (col 2t+1)
    {
      float xx = stg[ra & 127][2 * t + 1];
      sv[0] = ((unsigned)ra < 512u) ? xx : 0.0f;
    }
#pragma unroll
    for (int k = 1; k <= 15; ++k) {
      int row = ra + k;
      float2 xy = *(const float2*)&stg[row & 127][2 * t];
      bool ok = (unsigned)row < 512u;
      sv[2 * k - 1] = ok ? xy.x : 0.0f;        // even L (col 2t)
      sv[2 * k]     = ok ? xy.y : 0.0f;        // odd  L (col 2t+1)
    }
    {
      int row = ra + 16;
      float xx = stg[row & 127][2 * t];
      sv[31] = ((unsigned)row < 512u) ? xx : 0.0f;
    }

    // serial chain: dpp + add + add + mul per half-step
#pragma unroll
    for (int qq = 0; qq < 32; qq += 2) {
      {  // odd L: v1 = s*(shl(v0) + v0 + v1)
        float a = dpp_shl1(v0);                // lane 63 -> 0
        v1 = sv[qq] * (a + v0 + v1);
      }
      {  // even L: v0 = s*(v1 + shr(v1) + v0)
        float bb = dpp_shr1(v1);               // lane 0 -> 0
        v0 = sv[qq + 1] * (v1 + bb + v0);
      }
    }

    // chunk-boundary renormalize via DPP wave-max (lane 63 holds max)
    float mx = fmaxf(v0, v1);
    mx = dpp_max<0x111>(mx);                   // row_shr:1
    mx = dpp_max<0x112>(mx);                   // row_shr:2
    mx = dpp_max<0x114>(mx);                   // row_shr:4
    mx = dpp_max<0x118>(mx);                   // row_shr:8
    mx = dpp_max<0x142>(mx);                   // row_bcast:15
    mx = dpp_max<0x143>(mx);                   // row_bcast:31
    float mxs = __int_as_float(
        __builtin_amdgcn_readlane(__float_as_int(mx), 63));
    int e = (int)((__float_as_uint(mxs) >> 23) & 255u) - 127;
    float scale = __uint_as_float((unsigned)(127 - e) << 23);
    v0 *= scale; v1 *= scale;
    otally += e;
  }

  // R'[512][512] = -(log2(W) + sum e); raw = R' * ln2
  if (t == 32) raw[m] = -(LOG2F(v0) + (float)otally) * LN2;
}

// ---------------------------------------------------------------------------
// Kernel 4: combine + MSE
// ---------------------------------------------------------------------------
__global__ __launch_bounds__(64) void combine_kernel(
    const float* __restrict__ raw, const float* __restrict__ labels,
    float* __restrict__ out) {
  int lane = threadIdx.x;
  float val = 0.0f;
  if (lane < BATCH) {
    float r0 = raw[0 * BATCH + lane];
    float r1 = raw[1 * BATCH + lane];
    float r2 = raw[2 * BATCH + lane];
    float r3 = raw[3 * BATCH + lane];
    float diff = r0 - r1 - 0.5f * r2 + 0.5f * r3;
    float e = diff - labels[lane];
    val = e * e;
  }
#pragma unroll
  for (int off = 32; off; off >>= 1) val += __shfl_xor(val, off);
  if (lane == 0) out[0] = val * (1.0f / BATCH);
}

// ---------------------------------------------------------------------------
extern "C" void kernel_launch(void* const* d_in, const int* in_sizes, int n_in,
                              void* d_out, int out_size, void* d_ws, size_t ws_size,
                              hipStream_t stream) {
  const float* TGT = (const float*)d_in[0];
  const float* OTH = (const float*)d_in[1];
  const float* X   = (const float*)d_in[2];
  const float* labels = (const float*)d_in[3];
  float* out = (float*)d_out;

  char* ws = (char*)d_ws;
  float* Sband = (float*)ws;                                   // 32 MB
  size_t sband_bytes = (size_t)NMAT * SEQ * 128 * 4;
  unsigned short* Y = (unsigned short*)(ws + sband_bytes);     // 24 MB
  float* raw = (float*)(ws + sband_bytes + (size_t)3 * BATCH * SEQ * 256 * 2);

  hipLaunchKernelGGL(prep_kernel, dim3((3 * BATCH * SEQ) / 4), dim3(256), 0, stream,
                     TGT, OTH, X, Y);
  hipLaunchKernelGGL(costmm_kernel, dim3(8, NMAT), dim3(256), 0, stream, Y, Sband);
  hipLaunchKernelGGL(dtw_kernel, dim3(NMAT), dim3(64), 0, stream, Sband, raw);
  hipLaunchKernelGGL(combine_kernel, dim3(1), dim3(64), 0, stream, raw, labels, out);
}